// Round 2
// baseline (357.276 us; speedup 1.0000x reference)
//
#include <hip/hip_runtime.h>
#include <hip/hip_bf16.h>

// KMeans assign via fp16 coarse MFMA + exact fp32 fixup of near-tie rows.
// argmin_k ||xe - c_k|| == argmin_k ( ||c_k||^2 - 2*xe.c_k ),  xe = x + 1e-6.
// Coarse fp16 dot error sigma ~0.016 (sq-dist units); rows with coarse
// top2 gap < TAU=0.3 (~13 sigma) are exactly rescored in fp32.
//
// R1 (resubmit; previous round died on container-acquire infra failure):
// dist_f16 rework — double-buffered LDS with prefetch-before-compute
// (1 barrier/K-step instead of 2; load latency hides under ds_read+MFMA of
// the current tile) + both-sides XOR swizzle of the 16B LDS slots
// (slot ^= (row&3)^((row>>2)&3)) to kill the 8-way ds_read_b128 bank
// conflict. Source chunk index is pre-swizzled so global_load_lds' linear
// LDS write produces the swizzled layout (rule: both-sides-or-neither).

#define EPS 1e-6f
#define TAU 0.3f

constexpr int BROWS = 32768;   // 8*4096 rows
constexpr int DD    = 512;
constexpr int KC    = 2048;    // centroids
constexpr int FCAP  = 4096;    // max flagged rows handled exactly

typedef _Float16 half8  __attribute__((ext_vector_type(8)));
typedef _Float16 half4v __attribute__((ext_vector_type(4)));
typedef float    f32x4  __attribute__((ext_vector_type(4)));

// ---------------- prep: x -> fp16 (with eps) --------------------------------
__global__ __launch_bounds__(256) void prep_x(const float* __restrict__ x,
                                              _Float16* __restrict__ xh) {
    size_t i = ((size_t)blockIdx.x * 256 + threadIdx.x) * 4;
    float4 v = *(const float4*)(x + i);
    half4v h;
    h[0] = (_Float16)(v.x + EPS); h[1] = (_Float16)(v.y + EPS);
    h[2] = (_Float16)(v.z + EPS); h[3] = (_Float16)(v.w + EPS);
    *(half4v*)(xh + i) = h;
}

// ---------------- prep: centroids -> fp16, plus fp32 csq --------------------
__global__ __launch_bounds__(256) void prep_c(const float* __restrict__ cen,
                                              _Float16* __restrict__ ch,
                                              float* __restrict__ csq) {
    int w = threadIdx.x >> 6, lane = threadIdx.x & 63;
    int c = blockIdx.x * 4 + w;                    // grid 512 -> 2048 rows
    const float* row = cen + (size_t)c * DD;
    float4 v0 = *(const float4*)(row + lane * 8);
    float4 v1 = *(const float4*)(row + lane * 8 + 4);
    half8 h;
    h[0] = (_Float16)v0.x; h[1] = (_Float16)v0.y; h[2] = (_Float16)v0.z; h[3] = (_Float16)v0.w;
    h[4] = (_Float16)v1.x; h[5] = (_Float16)v1.y; h[6] = (_Float16)v1.z; h[7] = (_Float16)v1.w;
    *(half8*)(ch + (size_t)c * DD + lane * 8) = h;
    float s = v0.x*v0.x + v0.y*v0.y + v0.z*v0.z + v0.w*v0.w
            + v1.x*v1.x + v1.y*v1.y + v1.z*v1.z + v1.w*v1.w;
    #pragma unroll
    for (int off = 32; off > 0; off >>= 1) s += __shfl_down(s, off, 64);
    if (lane == 0) csq[c] = s;
}

// ---------------- coarse fp16 MFMA distance + per-row top2 ------------------
// 128x128 tile, 16x16x32_f16, global_load_lds width=16 staging.
// Double-buffered LDS + prefetch; XOR-swizzled 16B slots (conflict-free reads).
__global__ __launch_bounds__(256) void dist_f16(const _Float16* __restrict__ xh,
                                                const _Float16* __restrict__ ch,
                                                const float* __restrict__ csq,
                                                float* __restrict__ pbest,
                                                float* __restrict__ psec,
                                                int*   __restrict__ pidx) {
    __shared__ __align__(16) _Float16 ash[2][128 * 32];
    __shared__ __align__(16) _Float16 bsh[2][128 * 32];

    const int tid = threadIdx.x;
    const int w = tid >> 6, lane = tid & 63;
    const int wr = w >> 1, wc = w & 1;
    const int quad = lane >> 4, u = lane & 15;
    const int rowBase = blockIdx.x * 128;
    const int colBase = blockIdx.y * 128;

    // Staging granules: g in [0,512), 16B each. LDS granule g = (row g>>2, slot g&3).
    // Source chunk is pre-swizzled: chunk = (g&3) ^ (r&3) ^ ((r>>2)&3), so LDS slot
    // s of row r holds global chunk s ^ swz(r).
    const int g0 = 128 * w + lane;
    const int g1 = g0 + 64;
    const int r0 = g0 >> 2, h0 = (g0 & 3) ^ (r0 & 3) ^ ((r0 >> 2) & 3);
    const int r1 = g1 >> 2, h1 = (g1 & 3) ^ (r1 & 3) ^ ((r1 >> 2) & 3);
    const _Float16* pa0 = xh + (size_t)(rowBase + r0) * DD + h0 * 8;
    const _Float16* pa1 = xh + (size_t)(rowBase + r1) * DD + h1 * 8;
    const _Float16* pb0 = ch + (size_t)(colBase + r0) * DD + h0 * 8;
    const _Float16* pb1 = ch + (size_t)(colBase + r1) * DD + h1 * 8;

    auto stage = [&](int buf, int kt) {
        const int off = kt * 32;
        __builtin_amdgcn_global_load_lds(
            (const __attribute__((address_space(1))) void*)(pa0 + off),
            (__attribute__((address_space(3))) void*)(&ash[buf][g0 * 8]), 16, 0, 0);
        __builtin_amdgcn_global_load_lds(
            (const __attribute__((address_space(1))) void*)(pb0 + off),
            (__attribute__((address_space(3))) void*)(&bsh[buf][g0 * 8]), 16, 0, 0);
        __builtin_amdgcn_global_load_lds(
            (const __attribute__((address_space(1))) void*)(pa1 + off),
            (__attribute__((address_space(3))) void*)(&ash[buf][g1 * 8]), 16, 0, 0);
        __builtin_amdgcn_global_load_lds(
            (const __attribute__((address_space(1))) void*)(pb1 + off),
            (__attribute__((address_space(3))) void*)(&bsh[buf][g1 * 8]), 16, 0, 0);
    };

    f32x4 acc[4][4] = {};

    // Read-side swizzled slot: row = base16 + u with base16 % 16 == 0, so
    // (row&3) == (u&3) and ((row>>2)&3) == ((u>>2)&3) — independent of f.
    const int slotA = quad ^ (u & 3) ^ ((u >> 2) & 3);

    stage(0, 0);
    __syncthreads();    // drains vmcnt(0): tile 0 resident

    for (int kc = 0; kc < DD / 32; kc++) {
        const int cur = kc & 1;
        if (kc + 1 < DD / 32) stage(cur ^ 1, kc + 1);   // prefetch next tile

        half8 af[4], bf[4];
        #pragma unroll
        for (int f = 0; f < 4; f++) {
            af[f] = *(const half8*)(&ash[cur][(wr * 64 + f * 16 + u) * 32 + slotA * 8]);
            bf[f] = *(const half8*)(&bsh[cur][(wc * 64 + f * 16 + u) * 32 + slotA * 8]);
        }
        #pragma unroll
        for (int fr = 0; fr < 4; fr++)
            #pragma unroll
            for (int fc = 0; fc < 4; fc++)
                acc[fr][fc] = __builtin_amdgcn_mfma_f32_16x16x32_f16(af[fr], bf[fc], acc[fr][fc], 0, 0, 0);

        __syncthreads();    // drains vmcnt(0)+lgkmcnt(0): prefetch landed, reads done
    }

    // epilogue: val = csq[col] - 2*dot; per-row top2 across 64 cols of this wave
    float cq[4];
    int   ci[4];
    #pragma unroll
    for (int fc = 0; fc < 4; fc++) {
        ci[fc] = colBase + wc * 64 + fc * 16 + u;
        cq[fc] = csq[ci[fc]];
    }
    const int cbi = blockIdx.y * 2 + wc;

    #pragma unroll
    for (int fr = 0; fr < 4; fr++) {
        #pragma unroll
        for (int reg = 0; reg < 4; reg++) {
            float b = 3.4e38f, s = 3.4e38f; int bi = 0x7fffffff;
            #pragma unroll
            for (int fc = 0; fc < 4; fc++) {
                float v = cq[fc] - 2.0f * acc[fr][fc][reg];
                int c = ci[fc];
                if (v < b || (v == b && c < bi)) { s = b; b = v; bi = c; }
                else if (v < s) s = v;
            }
            #pragma unroll
            for (int m = 1; m < 16; m <<= 1) {   // butterfly within quad (16 lanes)
                float ob = __shfl_xor(b, m, 64);
                int  obi = __shfl_xor(bi, m, 64);
                float os = __shfl_xor(s, m, 64);
                if (ob < b || (ob == b && obi < bi)) {
                    s = fminf(fminf(b, s), os); b = ob; bi = obi;
                } else {
                    s = fminf(s, fminf(ob, os));
                }
            }
            if (u == 0) {
                int grow = rowBase + wr * 64 + fr * 16 + quad * 4 + reg;
                pbest[cbi * BROWS + grow] = b;
                psec [cbi * BROWS + grow] = s;
                pidx [cbi * BROWS + grow] = bi;
            }
        }
    }
}

// ---------------- merge 32 partials per row; flag near-ties -----------------
__global__ __launch_bounds__(256) void reduce_rows(const float* __restrict__ pbest,
                                                   const float* __restrict__ psec,
                                                   const int* __restrict__ pidx,
                                                   float* __restrict__ out,
                                                   int* __restrict__ labels,
                                                   int* __restrict__ rlist,
                                                   int* __restrict__ ctr) {
    int row = blockIdx.x * 256 + threadIdx.x;    // grid 128
    float b = 3.4e38f, s = 3.4e38f; int bi = 0x7fffffff;
    for (int p = 0; p < 32; p++) {
        float v  = pbest[p * BROWS + row];
        float sv = psec [p * BROWS + row];
        int   vi = pidx [p * BROWS + row];
        if (v < b || (v == b && vi < bi)) { s = fminf(sv, fminf(b, s)); b = v; bi = vi; }
        else                              { s = fminf(s, fminf(v, sv)); }
    }
    out[row] = (float)bi;
    labels[row] = bi;
    if (s - b < TAU) {
        int slot = atomicAdd(ctr, 1);
        if (slot < FCAP) rlist[slot] = row;
    }
}

// ---------------- exact fp32 rescore of flagged rows (R2 structure) ---------
__global__ __launch_bounds__(256, 2) void fixup_dist(const float* __restrict__ x,
                                                     const float* __restrict__ cen,
                                                     const float* __restrict__ csq,
                                                     const int* __restrict__ rlist,
                                                     const int* __restrict__ ctr,
                                                     float* __restrict__ fbest,
                                                     int*   __restrict__ fidx) {
    int n = min(*ctr, FCAP);
    int tilebase = blockIdx.y * 128;
    if (tilebase >= n) return;

    __shared__ float xs[16][132];
    __shared__ float cs[16][132];
    __shared__ float redv[128][17];
    __shared__ int   redi[128][17];
    __shared__ int   rows[128];

    const int tid = threadIdx.x;
    if (tid < 128) rows[tid] = rlist[tilebase + tid];
    __syncthreads();

    const int ty = tid >> 4, tx = tid & 15;
    const int colBase = blockIdx.x * 128;

    float acc[8][8] = {};
    for (int dk = 0; dk < DD; dk += 16) {
        #pragma unroll
        for (int sI = 0; sI < 2; sI++) {
            int id = tid + sI * 256;
            int r  = id >> 2;
            int dc = (id & 3) * 4;
            float4 xv = *(const float4*)(x + (size_t)rows[r] * DD + dk + dc);
            xs[dc + 0][r] = xv.x + EPS; xs[dc + 1][r] = xv.y + EPS;
            xs[dc + 2][r] = xv.z + EPS; xs[dc + 3][r] = xv.w + EPS;
            float4 cv = *(const float4*)(cen + (size_t)(colBase + r) * DD + dk + dc);
            cs[dc + 0][r] = cv.x; cs[dc + 1][r] = cv.y;
            cs[dc + 2][r] = cv.z; cs[dc + 3][r] = cv.w;
        }
        __syncthreads();
        #pragma unroll
        for (int k = 0; k < 16; k++) {
            float4 a0 = *(const float4*)&xs[k][ty * 4];
            float4 a1 = *(const float4*)&xs[k][64 + ty * 4];
            float4 b0 = *(const float4*)&cs[k][tx * 4];
            float4 b1 = *(const float4*)&cs[k][64 + tx * 4];
            float a[8] = {a0.x, a0.y, a0.z, a0.w, a1.x, a1.y, a1.z, a1.w};
            float b[8] = {b0.x, b0.y, b0.z, b0.w, b1.x, b1.y, b1.z, b1.w};
            #pragma unroll
            for (int i = 0; i < 8; i++)
                #pragma unroll
                for (int j = 0; j < 8; j++)
                    acc[i][j] += a[i] * b[j];
        }
        __syncthreads();
    }

    float bv[8]; int bix[8];
    #pragma unroll
    for (int i = 0; i < 8; i++) { bv[i] = 3.4e38f; bix[i] = 0x7fffffff; }
    #pragma unroll
    for (int j = 0; j < 8; j++) {
        int col = colBase + ((j < 4) ? (tx * 4 + j) : (64 + tx * 4 + (j - 4)));
        float cq = csq[col];
        #pragma unroll
        for (int i = 0; i < 8; i++) {
            float v = cq - 2.0f * acc[i][j];
            if (v < bv[i] || (v == bv[i] && col < bix[i])) { bv[i] = v; bix[i] = col; }
        }
    }
    #pragma unroll
    for (int i = 0; i < 8; i++) {
        int r = (i < 4) ? (ty * 4 + i) : (64 + ty * 4 + (i - 4));
        redv[r][tx] = bv[i]; redi[r][tx] = bix[i];
    }
    __syncthreads();
    if (tid < 128) {
        float b = 3.4e38f; int bi = 0x7fffffff;
        #pragma unroll
        for (int t = 0; t < 16; t++) {
            float v = redv[tid][t]; int ix = redi[tid][t];
            if (v < b || (v == b && ix < bi)) { b = v; bi = ix; }
        }
        fbest[blockIdx.x * FCAP + tilebase + tid] = b;
        fidx [blockIdx.x * FCAP + tilebase + tid] = bi;
    }
}

__global__ __launch_bounds__(256) void fixup_reduce(const float* __restrict__ fbest,
                                                    const int* __restrict__ fidx,
                                                    const int* __restrict__ rlist,
                                                    const int* __restrict__ ctr,
                                                    float* __restrict__ out,
                                                    int* __restrict__ labels) {
    int s = blockIdx.x * 256 + threadIdx.x;      // grid 16
    int n = min(*ctr, FCAP);
    if (s >= n) return;
    float b = 3.4e38f; int bi = 0x7fffffff;
    for (int c = 0; c < 16; c++) {
        float v = fbest[c * FCAP + s]; int ix = fidx[c * FCAP + s];
        if (v < b || (v == b && ix < bi)) { b = v; bi = ix; }
    }
    int row = rlist[s];
    out[row] = (float)bi;
    labels[row] = bi;
}

// ---------------- gather assigned centroids ---------------------------------
__global__ __launch_bounds__(256) void gather(const float* __restrict__ cen,
                                              const int* __restrict__ labels,
                                              float* __restrict__ out) {
    __shared__ int lab[8];
    const int tid = threadIdx.x;
    const int rowBase = blockIdx.x * 8;
    if (tid < 8) lab[tid] = labels[rowBase + tid];
    __syncthreads();
    float* assigned = out + BROWS;
    #pragma unroll 4
    for (int s = tid; s < 8 * 128; s += 256) {
        int r = s >> 7;
        int f = (s & 127) * 4;
        float4 v = *(const float4*)(cen + (size_t)lab[r] * DD + f);
        *(float4*)(assigned + (size_t)(rowBase + r) * DD + f) = v;
    }
}

extern "C" void kernel_launch(void* const* d_in, const int* in_sizes, int n_in,
                              void* d_out, int out_size, void* d_ws, size_t ws_size,
                              hipStream_t stream) {
    const float* x   = (const float*)d_in[0];
    const float* cen = (const float*)d_in[1];

    char* base = (char*)d_ws;
    _Float16* xh   = (_Float16*)(base);                    // 32 MB
    _Float16* ch   = (_Float16*)(base + 33554432);         // 2 MB
    float* csq     = (float*)(base + 35651584);            // 8 KB
    float* pbest   = (float*)(base + 35659776);            // 4 MB
    float* psec    = (float*)(base + 39854080);            // 4 MB
    int*   pidx    = (int*)  (base + 44048384);            // 4 MB
    int*   labels  = (int*)  (base + 48242688);            // 128 KB
    int*   rlist   = (int*)  (base + 48373760);            // 16 KB
    float* fbest   = (float*)(base + 48390144);            // 256 KB
    int*   fidx    = (int*)  (base + 48652288);            // 256 KB
    int*   ctr     = (int*)  (base + 48914432);            // 4 B

    hipMemsetAsync(ctr, 0, 4, stream);
    hipMemsetAsync(rlist, 0, FCAP * 4, stream);

    prep_x<<<BROWS * DD / 4 / 256, 256, 0, stream>>>(x, xh);
    prep_c<<<KC / 4, 256, 0, stream>>>(cen, ch, csq);
    dist_f16<<<dim3(BROWS / 128, KC / 128), 256, 0, stream>>>(xh, ch, csq, pbest, psec, pidx);
    reduce_rows<<<BROWS / 256, 256, 0, stream>>>(pbest, psec, pidx, (float*)d_out, labels, rlist, ctr);
    fixup_dist<<<dim3(KC / 128, FCAP / 128), 256, 0, stream>>>(x, cen, csq, rlist, ctr, fbest, fidx);
    fixup_reduce<<<FCAP / 256, 256, 0, stream>>>(fbest, fidx, rlist, ctr, (float*)d_out, labels);
    gather<<<BROWS / 8, 256, 0, stream>>>(cen, labels, (float*)d_out);
}

// Round 3
// 336.044 us; speedup vs baseline: 1.0632x; 1.0632x over previous
//
#include <hip/hip_runtime.h>
#include <hip/hip_bf16.h>

// KMeans assign via fp16 coarse MFMA + exact fp32 fixup of near-tie rows.
// argmin_k ||xe - c_k|| == argmin_k ( ||c_k||^2 - 2*xe.c_k ),  xe = x + 1e-6.
// Rows with coarse top2 gap < TAU=0.3 are exactly rescored in fp32.
//
// R2: occupancy + epilogue. R1 post-mortem: SQ_LDS_BANK_CONFLICT = exactly
// 8 cyc per global_load_lds (DMA-write fixed cost, NOT read conflicts —
// swizzle was a no-op, reverted). Kernel is latency-bound at 31% occupancy:
// 132 unified regs -> 3 waves/SIMD. Fix: __launch_bounds__(256,4) forces
// <=128 regs -> 4 waves/SIMD; epilogue rewritten (min/max top2 network,
// 2-word butterfly, ballot-based argmin recovery — coarse tie-break not
// needed since ties are always flagged and exactly rescored).

#define EPS 1e-6f
#define TAU 0.3f

constexpr int BROWS = 32768;   // 8*4096 rows
constexpr int DD    = 512;
constexpr int KC    = 2048;    // centroids
constexpr int FCAP  = 4096;    // max flagged rows handled exactly

typedef _Float16 half8  __attribute__((ext_vector_type(8)));
typedef _Float16 half4v __attribute__((ext_vector_type(4)));
typedef float    f32x4  __attribute__((ext_vector_type(4)));

// ---------------- prep: x -> fp16 (with eps) --------------------------------
__global__ __launch_bounds__(256) void prep_x(const float* __restrict__ x,
                                              _Float16* __restrict__ xh) {
    size_t i = ((size_t)blockIdx.x * 256 + threadIdx.x) * 4;
    float4 v = *(const float4*)(x + i);
    half4v h;
    h[0] = (_Float16)(v.x + EPS); h[1] = (_Float16)(v.y + EPS);
    h[2] = (_Float16)(v.z + EPS); h[3] = (_Float16)(v.w + EPS);
    *(half4v*)(xh + i) = h;
}

// ---------------- prep: centroids -> fp16, plus fp32 csq --------------------
__global__ __launch_bounds__(256) void prep_c(const float* __restrict__ cen,
                                              _Float16* __restrict__ ch,
                                              float* __restrict__ csq) {
    int w = threadIdx.x >> 6, lane = threadIdx.x & 63;
    int c = blockIdx.x * 4 + w;                    // grid 512 -> 2048 rows
    const float* row = cen + (size_t)c * DD;
    float4 v0 = *(const float4*)(row + lane * 8);
    float4 v1 = *(const float4*)(row + lane * 8 + 4);
    half8 h;
    h[0] = (_Float16)v0.x; h[1] = (_Float16)v0.y; h[2] = (_Float16)v0.z; h[3] = (_Float16)v0.w;
    h[4] = (_Float16)v1.x; h[5] = (_Float16)v1.y; h[6] = (_Float16)v1.z; h[7] = (_Float16)v1.w;
    *(half8*)(ch + (size_t)c * DD + lane * 8) = h;
    float s = v0.x*v0.x + v0.y*v0.y + v0.z*v0.z + v0.w*v0.w
            + v1.x*v1.x + v1.y*v1.y + v1.z*v1.z + v1.w*v1.w;
    #pragma unroll
    for (int off = 32; off > 0; off >>= 1) s += __shfl_down(s, off, 64);
    if (lane == 0) csq[c] = s;
}

// ---------------- coarse fp16 MFMA distance + per-row top2 ------------------
// 128x128 tile, 16x16x32_f16, global_load_lds width=16 staging, double-buffer.
// __launch_bounds__(256,4): cap at 128 unified regs -> 4 waves/SIMD.
__global__ __launch_bounds__(256, 4) void dist_f16(const _Float16* __restrict__ xh,
                                                   const _Float16* __restrict__ ch,
                                                   const float* __restrict__ csq,
                                                   float* __restrict__ pbest,
                                                   float* __restrict__ psec,
                                                   int*   __restrict__ pidx) {
    __shared__ __align__(16) _Float16 ash[2][128 * 32];
    __shared__ __align__(16) _Float16 bsh[2][128 * 32];

    const int tid = threadIdx.x;
    const int w = tid >> 6, lane = tid & 63;
    const int wr = w >> 1, wc = w & 1;
    const int quad = lane >> 4, u = lane & 15;
    const int rowBase = blockIdx.x * 128;
    const int colBase = blockIdx.y * 128;

    // Staging granules: g in [0,512), 16B each -> LDS row g>>2, 16B-slot g&3.
    const int g0 = 128 * w + lane;
    const int g1 = g0 + 64;
    const int r0 = g0 >> 2, h0 = g0 & 3;
    const int r1 = g1 >> 2, h1 = g1 & 3;
    const _Float16* pa0 = xh + (size_t)(rowBase + r0) * DD + h0 * 8;
    const _Float16* pa1 = xh + (size_t)(rowBase + r1) * DD + h1 * 8;
    const _Float16* pb0 = ch + (size_t)(colBase + r0) * DD + h0 * 8;
    const _Float16* pb1 = ch + (size_t)(colBase + r1) * DD + h1 * 8;

    auto stage = [&](int buf, int kt) {
        const int off = kt * 32;
        __builtin_amdgcn_global_load_lds(
            (const __attribute__((address_space(1))) void*)(pa0 + off),
            (__attribute__((address_space(3))) void*)(&ash[buf][g0 * 8]), 16, 0, 0);
        __builtin_amdgcn_global_load_lds(
            (const __attribute__((address_space(1))) void*)(pb0 + off),
            (__attribute__((address_space(3))) void*)(&bsh[buf][g0 * 8]), 16, 0, 0);
        __builtin_amdgcn_global_load_lds(
            (const __attribute__((address_space(1))) void*)(pa1 + off),
            (__attribute__((address_space(3))) void*)(&ash[buf][g1 * 8]), 16, 0, 0);
        __builtin_amdgcn_global_load_lds(
            (const __attribute__((address_space(1))) void*)(pb1 + off),
            (__attribute__((address_space(3))) void*)(&bsh[buf][g1 * 8]), 16, 0, 0);
    };

    f32x4 acc[4][4] = {};

    stage(0, 0);
    __syncthreads();    // tile 0 resident

    for (int kc = 0; kc < DD / 32; kc++) {
        const int cur = kc & 1;
        if (kc + 1 < DD / 32) stage(cur ^ 1, kc + 1);   // prefetch next tile

        half8 af[4], bf[4];
        #pragma unroll
        for (int f = 0; f < 4; f++) {
            af[f] = *(const half8*)(&ash[cur][(wr * 64 + f * 16 + u) * 32 + quad * 8]);
            bf[f] = *(const half8*)(&bsh[cur][(wc * 64 + f * 16 + u) * 32 + quad * 8]);
        }
        #pragma unroll
        for (int fr = 0; fr < 4; fr++)
            #pragma unroll
            for (int fc = 0; fc < 4; fc++)
                acc[fr][fc] = __builtin_amdgcn_mfma_f32_16x16x32_f16(af[fr], bf[fc], acc[fr][fc], 0, 0, 0);

        __syncthreads();
    }

    // epilogue: val = csq[col] - 2*dot; per-row top2 across 64 cols per wave.
    // Coarse pass needs NO index tie-break: exact ties -> gap 0 < TAU ->
    // flagged -> fp32 fixup decides. So: pure min/max top2 + ballot argmin.
    float cq[4];
    #pragma unroll
    for (int fc = 0; fc < 4; fc++) cq[fc] = csq[colBase + wc * 64 + fc * 16 + u];
    const int cbi = blockIdx.y * 2 + wc;
    const int colQuadBase = colBase + wc * 64;   // col = colQuadBase + fc*16 + laneu

    #pragma unroll
    for (int fr = 0; fr < 4; fr++) {
        #pragma unroll
        for (int reg = 0; reg < 4; reg++) {
            float vv[4];
            #pragma unroll
            for (int fc = 0; fc < 4; fc++) vv[fc] = cq[fc] - 2.0f * acc[fr][fc][reg];
            // top2 of 4 (min/max network)
            float mn01 = fminf(vv[0], vv[1]), mx01 = fmaxf(vv[0], vv[1]);
            float mn23 = fminf(vv[2], vv[3]), mx23 = fmaxf(vv[2], vv[3]);
            float b = fminf(mn01, mn23);
            float s = fminf(fmaxf(mn01, mn23), fminf(mx01, mx23));
            // butterfly over the 16 lanes of this quad (masks < 16)
            #pragma unroll
            for (int m = 1; m < 16; m <<= 1) {
                float ob = __shfl_xor(b, m, 64);
                float os = __shfl_xor(s, m, 64);
                s = fminf(fminf(s, os), fmaxf(b, ob));
                b = fminf(b, ob);
            }
            // argmin recovery: b is uniform within the quad; first match in
            // (fc, u) order == smallest col.
            int bi = 0x7fffffff;
            #pragma unroll
            for (int fc = 0; fc < 4; fc++) {
                unsigned long long mm = __ballot(vv[fc] == b);
                unsigned q16 = (unsigned)((mm >> (quad * 16)) & 0xFFFFu);
                if (bi == 0x7fffffff && q16)
                    bi = colQuadBase + fc * 16 + (__ffs(q16) - 1);
            }
            if (u == 0) {
                int grow = rowBase + wr * 64 + fr * 16 + quad * 4 + reg;
                pbest[cbi * BROWS + grow] = b;
                psec [cbi * BROWS + grow] = s;
                pidx [cbi * BROWS + grow] = bi;
            }
        }
    }
}

// ---------------- merge 32 partials per row; flag near-ties -----------------
__global__ __launch_bounds__(256) void reduce_rows(const float* __restrict__ pbest,
                                                   const float* __restrict__ psec,
                                                   const int* __restrict__ pidx,
                                                   float* __restrict__ out,
                                                   int* __restrict__ labels,
                                                   int* __restrict__ rlist,
                                                   int* __restrict__ ctr) {
    int row = blockIdx.x * 256 + threadIdx.x;    // grid 128
    float b = 3.4e38f, s = 3.4e38f; int bi = 0x7fffffff;
    for (int p = 0; p < 32; p++) {
        float v  = pbest[p * BROWS + row];
        float sv = psec [p * BROWS + row];
        int   vi = pidx [p * BROWS + row];
        if (v < b) { s = fminf(b, fminf(s, sv)); b = v; bi = vi; }
        else       { s = fminf(s, fminf(v, sv)); }
    }
    out[row] = (float)bi;
    labels[row] = bi;
    if (s - b < TAU) {
        int slot = atomicAdd(ctr, 1);
        if (slot < FCAP) rlist[slot] = row;
    }
}

// ---------------- exact fp32 rescore of flagged rows ------------------------
__global__ __launch_bounds__(256, 2) void fixup_dist(const float* __restrict__ x,
                                                     const float* __restrict__ cen,
                                                     const float* __restrict__ csq,
                                                     const int* __restrict__ rlist,
                                                     const int* __restrict__ ctr,
                                                     float* __restrict__ fbest,
                                                     int*   __restrict__ fidx) {
    int n = min(*ctr, FCAP);
    int tilebase = blockIdx.y * 128;
    if (tilebase >= n) return;

    __shared__ float xs[16][132];
    __shared__ float cs[16][132];
    __shared__ float redv[128][17];
    __shared__ int   redi[128][17];
    __shared__ int   rows[128];

    const int tid = threadIdx.x;
    if (tid < 128) rows[tid] = rlist[tilebase + tid];
    __syncthreads();

    const int ty = tid >> 4, tx = tid & 15;
    const int colBase = blockIdx.x * 128;

    float acc[8][8] = {};
    for (int dk = 0; dk < DD; dk += 16) {
        #pragma unroll
        for (int sI = 0; sI < 2; sI++) {
            int id = tid + sI * 256;
            int r  = id >> 2;
            int dc = (id & 3) * 4;
            float4 xv = *(const float4*)(x + (size_t)rows[r] * DD + dk + dc);
            xs[dc + 0][r] = xv.x + EPS; xs[dc + 1][r] = xv.y + EPS;
            xs[dc + 2][r] = xv.z + EPS; xs[dc + 3][r] = xv.w + EPS;
            float4 cv = *(const float4*)(cen + (size_t)(colBase + r) * DD + dk + dc);
            cs[dc + 0][r] = cv.x; cs[dc + 1][r] = cv.y;
            cs[dc + 2][r] = cv.z; cs[dc + 3][r] = cv.w;
        }
        __syncthreads();
        #pragma unroll
        for (int k = 0; k < 16; k++) {
            float4 a0 = *(const float4*)&xs[k][ty * 4];
            float4 a1 = *(const float4*)&xs[k][64 + ty * 4];
            float4 b0 = *(const float4*)&cs[k][tx * 4];
            float4 b1 = *(const float4*)&cs[k][64 + tx * 4];
            float a[8] = {a0.x, a0.y, a0.z, a0.w, a1.x, a1.y, a1.z, a1.w};
            float b[8] = {b0.x, b0.y, b0.z, b0.w, b1.x, b1.y, b1.z, b1.w};
            #pragma unroll
            for (int i = 0; i < 8; i++)
                #pragma unroll
                for (int j = 0; j < 8; j++)
                    acc[i][j] += a[i] * b[j];
        }
        __syncthreads();
    }

    float bv[8]; int bix[8];
    #pragma unroll
    for (int i = 0; i < 8; i++) { bv[i] = 3.4e38f; bix[i] = 0x7fffffff; }
    #pragma unroll
    for (int j = 0; j < 8; j++) {
        int col = colBase + ((j < 4) ? (tx * 4 + j) : (64 + tx * 4 + (j - 4)));
        float cq = csq[col];
        #pragma unroll
        for (int i = 0; i < 8; i++) {
            float v = cq - 2.0f * acc[i][j];
            if (v < bv[i] || (v == bv[i] && col < bix[i])) { bv[i] = v; bix[i] = col; }
        }
    }
    #pragma unroll
    for (int i = 0; i < 8; i++) {
        int r = (i < 4) ? (ty * 4 + i) : (64 + ty * 4 + (i - 4));
        redv[r][tx] = bv[i]; redi[r][tx] = bix[i];
    }
    __syncthreads();
    if (tid < 128) {
        float b = 3.4e38f; int bi = 0x7fffffff;
        #pragma unroll
        for (int t = 0; t < 16; t++) {
            float v = redv[tid][t]; int ix = redi[tid][t];
            if (v < b || (v == b && ix < bi)) { b = v; bi = ix; }
        }
        fbest[blockIdx.x * FCAP + tilebase + tid] = b;
        fidx [blockIdx.x * FCAP + tilebase + tid] = bi;
    }
}

__global__ __launch_bounds__(256) void fixup_reduce(const float* __restrict__ fbest,
                                                    const int* __restrict__ fidx,
                                                    const int* __restrict__ rlist,
                                                    const int* __restrict__ ctr,
                                                    float* __restrict__ out,
                                                    int* __restrict__ labels) {
    int s = blockIdx.x * 256 + threadIdx.x;      // grid 16
    int n = min(*ctr, FCAP);
    if (s >= n) return;
    float b = 3.4e38f; int bi = 0x7fffffff;
    for (int c = 0; c < 16; c++) {
        float v = fbest[c * FCAP + s]; int ix = fidx[c * FCAP + s];
        if (v < b || (v == b && ix < bi)) { b = v; bi = ix; }
    }
    int row = rlist[s];
    out[row] = (float)bi;
    labels[row] = bi;
}

// ---------------- gather assigned centroids ---------------------------------
__global__ __launch_bounds__(256) void gather(const float* __restrict__ cen,
                                              const int* __restrict__ labels,
                                              float* __restrict__ out) {
    __shared__ int lab[8];
    const int tid = threadIdx.x;
    const int rowBase = blockIdx.x * 8;
    if (tid < 8) lab[tid] = labels[rowBase + tid];
    __syncthreads();
    float* assigned = out + BROWS;
    #pragma unroll 4
    for (int s = tid; s < 8 * 128; s += 256) {
        int r = s >> 7;
        int f = (s & 127) * 4;
        float4 v = *(const float4*)(cen + (size_t)lab[r] * DD + f);
        *(float4*)(assigned + (size_t)(rowBase + r) * DD + f) = v;
    }
}

extern "C" void kernel_launch(void* const* d_in, const int* in_sizes, int n_in,
                              void* d_out, int out_size, void* d_ws, size_t ws_size,
                              hipStream_t stream) {
    const float* x   = (const float*)d_in[0];
    const float* cen = (const float*)d_in[1];

    char* base = (char*)d_ws;
    _Float16* xh   = (_Float16*)(base);                    // 32 MB
    _Float16* ch   = (_Float16*)(base + 33554432);         // 2 MB
    float* csq     = (float*)(base + 35651584);            // 8 KB
    float* pbest   = (float*)(base + 35659776);            // 4 MB
    float* psec    = (float*)(base + 39854080);            // 4 MB
    int*   pidx    = (int*)  (base + 44048384);            // 4 MB
    int*   labels  = (int*)  (base + 48242688);            // 128 KB
    int*   rlist   = (int*)  (base + 48373760);            // 16 KB
    float* fbest   = (float*)(base + 48390144);            // 256 KB
    int*   fidx    = (int*)  (base + 48652288);            // 256 KB
    int*   ctr     = (int*)  (base + 48914432);            // 4 B

    hipMemsetAsync(ctr, 0, 4, stream);
    hipMemsetAsync(rlist, 0, FCAP * 4, stream);

    prep_x<<<BROWS * DD / 4 / 256, 256, 0, stream>>>(x, xh);
    prep_c<<<KC / 4, 256, 0, stream>>>(cen, ch, csq);
    dist_f16<<<dim3(BROWS / 128, KC / 128), 256, 0, stream>>>(xh, ch, csq, pbest, psec, pidx);
    reduce_rows<<<BROWS / 256, 256, 0, stream>>>(pbest, psec, pidx, (float*)d_out, labels, rlist, ctr);
    fixup_dist<<<dim3(KC / 128, FCAP / 128), 256, 0, stream>>>(x, cen, csq, rlist, ctr, fbest, fidx);
    fixup_reduce<<<FCAP / 256, 256, 0, stream>>>(fbest, fidx, rlist, ctr, (float*)d_out, labels);
    gather<<<BROWS / 8, 256, 0, stream>>>(cen, labels, (float*)d_out);
}

// Round 5
// 333.865 us; speedup vs baseline: 1.0701x; 1.0065x over previous
//
#include <hip/hip_runtime.h>
#include <hip/hip_bf16.h>

// KMeans assign via fp16 coarse MFMA + exact fp32 fixup of near-tie rows.
// argmin_k ||xe - c_k|| == argmin_k ( ||c_k||^2 - 2*xe.c_k ),  xe = x + 1e-6.
// Rows with coarse top2 gap < TAU=0.3 are exactly rescored in fp32.
//
// R3 (resubmit; previous round died on container-acquire infra failure):
// LDS-port bound fix. R2 post-mortem: MfmaUtil capped ~23% because LDS
// read BW (8KB/wave/K-step at 64x64 reg tile, 256B/clk/CU) exceeds MFMA
// demand; plus u==0-only 16B epilogue stores caused partial-line
// write-allocate (WRITE_SIZE 95MB vs 12.6 logical). Fix: 256x128 block tile,
// 4 waves of 128x64 (21.8 MAC/LDS-byte, +36%), and epilogue redistribution
// through LDS for fully-coalesced 128-contiguous stores.
// SQ_LDS_BANK_CONFLICT == 8cyc/global_load_lds is DMA fixed cost (verified
// R1/R2, identical counter) — not a read conflict; reads are 2-way (free).

#define EPS 1e-6f
#define TAU 0.3f

constexpr int BROWS = 32768;   // 8*4096 rows
constexpr int DD    = 512;
constexpr int KC    = 2048;    // centroids
constexpr int FCAP  = 4096;    // max flagged rows handled exactly

typedef _Float16 half8  __attribute__((ext_vector_type(8)));
typedef _Float16 half4v __attribute__((ext_vector_type(4)));
typedef float    f32x4  __attribute__((ext_vector_type(4)));

// ---------------- prep: x -> fp16 (with eps) --------------------------------
__global__ __launch_bounds__(256) void prep_x(const float* __restrict__ x,
                                              _Float16* __restrict__ xh) {
    size_t i = ((size_t)blockIdx.x * 256 + threadIdx.x) * 4;
    float4 v = *(const float4*)(x + i);
    half4v h;
    h[0] = (_Float16)(v.x + EPS); h[1] = (_Float16)(v.y + EPS);
    h[2] = (_Float16)(v.z + EPS); h[3] = (_Float16)(v.w + EPS);
    *(half4v*)(xh + i) = h;
}

// ---------------- prep: centroids -> fp16, plus fp32 csq --------------------
__global__ __launch_bounds__(256) void prep_c(const float* __restrict__ cen,
                                              _Float16* __restrict__ ch,
                                              float* __restrict__ csq) {
    int w = threadIdx.x >> 6, lane = threadIdx.x & 63;
    int c = blockIdx.x * 4 + w;                    // grid 512 -> 2048 rows
    const float* row = cen + (size_t)c * DD;
    float4 v0 = *(const float4*)(row + lane * 8);
    float4 v1 = *(const float4*)(row + lane * 8 + 4);
    half8 h;
    h[0] = (_Float16)v0.x; h[1] = (_Float16)v0.y; h[2] = (_Float16)v0.z; h[3] = (_Float16)v0.w;
    h[4] = (_Float16)v1.x; h[5] = (_Float16)v1.y; h[6] = (_Float16)v1.z; h[7] = (_Float16)v1.w;
    *(half8*)(ch + (size_t)c * DD + lane * 8) = h;
    float s = v0.x*v0.x + v0.y*v0.y + v0.z*v0.z + v0.w*v0.w
            + v1.x*v1.x + v1.y*v1.y + v1.z*v1.z + v1.w*v1.w;
    #pragma unroll
    for (int off = 32; off > 0; off >>= 1) s += __shfl_down(s, off, 64);
    if (lane == 0) csq[c] = s;
}

// ---------------- coarse fp16 MFMA distance + per-row top2 ------------------
// 256x128 block tile, 4 waves (2 row-groups x 2 col-groups), 128x64 per wave.
// 16x16x32_f16 MFMA, global_load_lds width=16, double-buffered LDS.
__global__ __launch_bounds__(256, 2) void dist_f16(const _Float16* __restrict__ xh,
                                                   const _Float16* __restrict__ ch,
                                                   const float* __restrict__ csq,
                                                   float* __restrict__ pbest,
                                                   float* __restrict__ psec,
                                                   int*   __restrict__ pidx) {
    __shared__ __align__(16) _Float16 ash[2][256 * 32];   // 32 KB
    __shared__ __align__(16) _Float16 bsh[2][128 * 32];   // 16 KB
    __shared__ float eb[4][128];                          // 2 KB
    __shared__ float es[4][128];                          // 2 KB
    __shared__ int   ei[4][128];                          // 2 KB

    const int tid = threadIdx.x;
    const int w = tid >> 6, lane = tid & 63;
    const int wr = w >> 1, wc = w & 1;
    const int quad = lane >> 4, u = lane & 15;
    const int rowBase = blockIdx.x * 256;
    const int colBase = blockIdx.y * 128;

    // Staging granules (16B each). A: 1024 granules (256 rows x 4 slots),
    // B: 512 granules. Granule g -> LDS row g>>2, slot g&3; wave-contiguous.
    const _Float16* gA[4];
    const _Float16* gB[2];
    int ldsA[4], ldsB[2];
    #pragma unroll
    for (int j = 0; j < 4; j++) {
        int g = w * 256 + j * 64 + lane;
        int r = g >> 2, h = g & 3;
        gA[j] = xh + (size_t)(rowBase + r) * DD + h * 8;
        ldsA[j] = g * 8;
    }
    #pragma unroll
    for (int j = 0; j < 2; j++) {
        int g = w * 128 + j * 64 + lane;
        int r = g >> 2, h = g & 3;
        gB[j] = ch + (size_t)(colBase + r) * DD + h * 8;
        ldsB[j] = g * 8;
    }

    auto stage = [&](int buf, int kt) {
        const int off = kt * 32;
        #pragma unroll
        for (int j = 0; j < 4; j++)
            __builtin_amdgcn_global_load_lds(
                (const __attribute__((address_space(1))) void*)(gA[j] + off),
                (__attribute__((address_space(3))) void*)(&ash[buf][ldsA[j]]), 16, 0, 0);
        #pragma unroll
        for (int j = 0; j < 2; j++)
            __builtin_amdgcn_global_load_lds(
                (const __attribute__((address_space(1))) void*)(gB[j] + off),
                (__attribute__((address_space(3))) void*)(&bsh[buf][ldsB[j]]), 16, 0, 0);
    };

    f32x4 acc[8][4] = {};

    stage(0, 0);
    __syncthreads();    // tile 0 resident

    for (int kc = 0; kc < DD / 32; kc++) {
        const int cur = kc & 1;
        if (kc + 1 < DD / 32) stage(cur ^ 1, kc + 1);   // prefetch next tile

        half8 af[8], bf[4];
        #pragma unroll
        for (int f = 0; f < 8; f++)
            af[f] = *(const half8*)(&ash[cur][(wr * 128 + f * 16 + u) * 32 + quad * 8]);
        #pragma unroll
        for (int f = 0; f < 4; f++)
            bf[f] = *(const half8*)(&bsh[cur][(wc * 64 + f * 16 + u) * 32 + quad * 8]);

        #pragma unroll
        for (int fr = 0; fr < 8; fr++)
            #pragma unroll
            for (int fc = 0; fc < 4; fc++)
                acc[fr][fc] = __builtin_amdgcn_mfma_f32_16x16x32_f16(af[fr], bf[fc], acc[fr][fc], 0, 0, 0);

        __syncthreads();
    }

    // epilogue: val = csq[col] - 2*dot; per-row top2 across this wave's 64
    // cols. No coarse index tie-break needed (ties -> gap 0 < TAU -> fixup).
    float cq[4];
    #pragma unroll
    for (int fc = 0; fc < 4; fc++) cq[fc] = csq[colBase + wc * 64 + fc * 16 + u];
    const int cbi = blockIdx.y * 2 + wc;
    const int colQuadBase = colBase + wc * 64;

    #pragma unroll
    for (int fr = 0; fr < 8; fr++) {
        #pragma unroll
        for (int reg = 0; reg < 4; reg++) {
            float vv[4];
            #pragma unroll
            for (int fc = 0; fc < 4; fc++) vv[fc] = cq[fc] - 2.0f * acc[fr][fc][reg];
            float mn01 = fminf(vv[0], vv[1]), mx01 = fmaxf(vv[0], vv[1]);
            float mn23 = fminf(vv[2], vv[3]), mx23 = fmaxf(vv[2], vv[3]);
            float b = fminf(mn01, mn23);
            float s = fminf(fmaxf(mn01, mn23), fminf(mx01, mx23));
            #pragma unroll
            for (int m = 1; m < 16; m <<= 1) {   // butterfly within quad
                float ob = __shfl_xor(b, m, 64);
                float os = __shfl_xor(s, m, 64);
                s = fminf(fminf(s, os), fmaxf(b, ob));
                b = fminf(b, ob);
            }
            int bi = 0x7fffffff;
            #pragma unroll
            for (int fc = 0; fc < 4; fc++) {
                unsigned long long mm = __ballot(vv[fc] == b);
                unsigned q16 = (unsigned)((mm >> (quad * 16)) & 0xFFFFu);
                if (bi == 0x7fffffff && q16)
                    bi = colQuadBase + fc * 16 + (__ffs(q16) - 1);
            }
            if (u == 0) {
                int rl = fr * 16 + quad * 4 + reg;   // local row 0..127
                eb[w][rl] = b; es[w][rl] = s; ei[w][rl] = bi;
            }
        }
    }
    __syncthreads();
    // coalesced partial stores: 128 contiguous rows per wave per array
    {
        const int base = cbi * BROWS + rowBase + wr * 128;
        pbest[base + lane]      = eb[w][lane];
        pbest[base + 64 + lane] = eb[w][64 + lane];
        psec [base + lane]      = es[w][lane];
        psec [base + 64 + lane] = es[w][64 + lane];
        pidx [base + lane]      = ei[w][lane];
        pidx [base + 64 + lane] = ei[w][64 + lane];
    }
}

// ---------------- merge 32 partials per row; flag near-ties -----------------
__global__ __launch_bounds__(256) void reduce_rows(const float* __restrict__ pbest,
                                                   const float* __restrict__ psec,
                                                   const int* __restrict__ pidx,
                                                   float* __restrict__ out,
                                                   int* __restrict__ labels,
                                                   int* __restrict__ rlist,
                                                   int* __restrict__ ctr) {
    int row = blockIdx.x * 256 + threadIdx.x;    // grid 128
    float b = 3.4e38f, s = 3.4e38f; int bi = 0x7fffffff;
    for (int p = 0; p < 32; p++) {
        float v  = pbest[p * BROWS + row];
        float sv = psec [p * BROWS + row];
        int   vi = pidx [p * BROWS + row];
        if (v < b) { s = fminf(b, fminf(s, sv)); b = v; bi = vi; }
        else       { s = fminf(s, fminf(v, sv)); }
    }
    out[row] = (float)bi;
    labels[row] = bi;
    if (s - b < TAU) {
        int slot = atomicAdd(ctr, 1);
        if (slot < FCAP) rlist[slot] = row;
    }
}

// ---------------- exact fp32 rescore of flagged rows ------------------------
__global__ __launch_bounds__(256, 2) void fixup_dist(const float* __restrict__ x,
                                                     const float* __restrict__ cen,
                                                     const float* __restrict__ csq,
                                                     const int* __restrict__ rlist,
                                                     const int* __restrict__ ctr,
                                                     float* __restrict__ fbest,
                                                     int*   __restrict__ fidx) {
    int n = min(*ctr, FCAP);
    int tilebase = blockIdx.y * 128;
    if (tilebase >= n) return;

    __shared__ float xs[16][132];
    __shared__ float cs[16][132];
    __shared__ float redv[128][17];
    __shared__ int   redi[128][17];
    __shared__ int   rows[128];

    const int tid = threadIdx.x;
    if (tid < 128) rows[tid] = rlist[tilebase + tid];
    __syncthreads();

    const int ty = tid >> 4, tx = tid & 15;
    const int colBase = blockIdx.x * 128;

    float acc[8][8] = {};
    for (int dk = 0; dk < DD; dk += 16) {
        #pragma unroll
        for (int sI = 0; sI < 2; sI++) {
            int id = tid + sI * 256;
            int r  = id >> 2;
            int dc = (id & 3) * 4;
            float4 xv = *(const float4*)(x + (size_t)rows[r] * DD + dk + dc);
            xs[dc + 0][r] = xv.x + EPS; xs[dc + 1][r] = xv.y + EPS;
            xs[dc + 2][r] = xv.z + EPS; xs[dc + 3][r] = xv.w + EPS;
            float4 cv = *(const float4*)(cen + (size_t)(colBase + r) * DD + dk + dc);
            cs[dc + 0][r] = cv.x; cs[dc + 1][r] = cv.y;
            cs[dc + 2][r] = cv.z; cs[dc + 3][r] = cv.w;
        }
        __syncthreads();
        #pragma unroll
        for (int k = 0; k < 16; k++) {
            float4 a0 = *(const float4*)&xs[k][ty * 4];
            float4 a1 = *(const float4*)&xs[k][64 + ty * 4];
            float4 b0 = *(const float4*)&cs[k][tx * 4];
            float4 b1 = *(const float4*)&cs[k][64 + tx * 4];
            float a[8] = {a0.x, a0.y, a0.z, a0.w, a1.x, a1.y, a1.z, a1.w};
            float b[8] = {b0.x, b0.y, b0.z, b0.w, b1.x, b1.y, b1.z, b1.w};
            #pragma unroll
            for (int i = 0; i < 8; i++)
                #pragma unroll
                for (int j = 0; j < 8; j++)
                    acc[i][j] += a[i] * b[j];
        }
        __syncthreads();
    }

    float bv[8]; int bix[8];
    #pragma unroll
    for (int i = 0; i < 8; i++) { bv[i] = 3.4e38f; bix[i] = 0x7fffffff; }
    #pragma unroll
    for (int j = 0; j < 8; j++) {
        int col = colBase + ((j < 4) ? (tx * 4 + j) : (64 + tx * 4 + (j - 4)));
        float cq = csq[col];
        #pragma unroll
        for (int i = 0; i < 8; i++) {
            float v = cq - 2.0f * acc[i][j];
            if (v < bv[i] || (v == bv[i] && col < bix[i])) { bv[i] = v; bix[i] = col; }
        }
    }
    #pragma unroll
    for (int i = 0; i < 8; i++) {
        int r = (i < 4) ? (ty * 4 + i) : (64 + ty * 4 + (i - 4));
        redv[r][tx] = bv[i]; redi[r][tx] = bix[i];
    }
    __syncthreads();
    if (tid < 128) {
        float b = 3.4e38f; int bi = 0x7fffffff;
        #pragma unroll
        for (int t = 0; t < 16; t++) {
            float v = redv[tid][t]; int ix = redi[tid][t];
            if (v < b || (v == b && ix < bi)) { b = v; bi = ix; }
        }
        fbest[blockIdx.x * FCAP + tilebase + tid] = b;
        fidx [blockIdx.x * FCAP + tilebase + tid] = bi;
    }
}

__global__ __launch_bounds__(256) void fixup_reduce(const float* __restrict__ fbest,
                                                    const int* __restrict__ fidx,
                                                    const int* __restrict__ rlist,
                                                    const int* __restrict__ ctr,
                                                    float* __restrict__ out,
                                                    int* __restrict__ labels) {
    int s = blockIdx.x * 256 + threadIdx.x;      // grid 16
    int n = min(*ctr, FCAP);
    if (s >= n) return;
    float b = 3.4e38f; int bi = 0x7fffffff;
    for (int c = 0; c < 16; c++) {
        float v = fbest[c * FCAP + s]; int ix = fidx[c * FCAP + s];
        if (v < b || (v == b && ix < bi)) { b = v; bi = ix; }
    }
    int row = rlist[s];
    out[row] = (float)bi;
    labels[row] = bi;
}

// ---------------- gather assigned centroids ---------------------------------
__global__ __launch_bounds__(256) void gather(const float* __restrict__ cen,
                                              const int* __restrict__ labels,
                                              float* __restrict__ out) {
    __shared__ int lab[8];
    const int tid = threadIdx.x;
    const int rowBase = blockIdx.x * 8;
    if (tid < 8) lab[tid] = labels[rowBase + tid];
    __syncthreads();
    float* assigned = out + BROWS;
    #pragma unroll 4
    for (int s = tid; s < 8 * 128; s += 256) {
        int r = s >> 7;
        int f = (s & 127) * 4;
        float4 v = *(const float4*)(cen + (size_t)lab[r] * DD + f);
        *(float4*)(assigned + (size_t)(rowBase + r) * DD + f) = v;
    }
}

extern "C" void kernel_launch(void* const* d_in, const int* in_sizes, int n_in,
                              void* d_out, int out_size, void* d_ws, size_t ws_size,
                              hipStream_t stream) {
    const float* x   = (const float*)d_in[0];
    const float* cen = (const float*)d_in[1];

    char* base = (char*)d_ws;
    _Float16* xh   = (_Float16*)(base);                    // 32 MB
    _Float16* ch   = (_Float16*)(base + 33554432);         // 2 MB
    float* csq     = (float*)(base + 35651584);            // 8 KB
    float* pbest   = (float*)(base + 35659776);            // 4 MB
    float* psec    = (float*)(base + 39854080);            // 4 MB
    int*   pidx    = (int*)  (base + 44048384);            // 4 MB
    int*   labels  = (int*)  (base + 48242688);            // 128 KB
    int*   rlist   = (int*)  (base + 48373760);            // 16 KB
    float* fbest   = (float*)(base + 48390144);            // 256 KB
    int*   fidx    = (int*)  (base + 48652288);            // 256 KB
    int*   ctr     = (int*)  (base + 48914432);            // 4 B

    hipMemsetAsync(ctr, 0, 4, stream);
    hipMemsetAsync(rlist, 0, FCAP * 4, stream);

    prep_x<<<BROWS * DD / 4 / 256, 256, 0, stream>>>(x, xh);
    prep_c<<<KC / 4, 256, 0, stream>>>(cen, ch, csq);
    dist_f16<<<dim3(BROWS / 256, KC / 128), 256, 0, stream>>>(xh, ch, csq, pbest, psec, pidx);
    reduce_rows<<<BROWS / 256, 256, 0, stream>>>(pbest, psec, pidx, (float*)d_out, labels, rlist, ctr);
    fixup_dist<<<dim3(KC / 128, FCAP / 128), 256, 0, stream>>>(x, cen, csq, rlist, ctr, fbest, fidx);
    fixup_reduce<<<FCAP / 256, 256, 0, stream>>>(fbest, fidx, rlist, ctr, (float*)d_out, labels);
    gather<<<BROWS / 8, 256, 0, stream>>>(cen, labels, (float*)d_out);
}

// Round 6
// 311.729 us; speedup vs baseline: 1.1461x; 1.0710x over previous
//
#include <hip/hip_runtime.h>
#include <hip/hip_bf16.h>

// KMeans assign via fp16 coarse MFMA + exact fp32 fixup of near-tie rows.
// argmin_k ||xe - c_k|| == argmin_k ( ||c_k||^2 - 2*xe.c_k ),  xe = x + 1e-6.
// Rows with coarse top2 gap < TAU=0.3 are exactly rescored in fp32.
//
// R4: counted-vmcnt pipeline (T3+T4). Occupancy tracks duration across all
// rounds -> latency-bound; the __syncthreads vmcnt(0) drain exposed full
// load latency every K-step. Now: 128x128 tile (R2 shape, 4 waves/SIMD),
// A triple-buffered (staged k+2, ~2 steps cover for L3/HBM), B double-
// buffered (staged k+1, L2-resident), s_waitcnt vmcnt(2) + raw s_barrier
// per step (vmcnt(0) only on the last step). LDS 40KB -> 4 blocks/CU
// (160KB exactly); epilogue staging overlays A-buffers after a barrier.
// SQ_LDS_BANK_CONFLICT == 8 cyc per global_load_lds DMA instr (fixed cost,
// verified R1/R2/R3 to the exact count) — reads are conflict-free.

#define EPS 1e-6f
#define TAU 0.3f

constexpr int BROWS = 32768;   // 8*4096 rows
constexpr int DD    = 512;
constexpr int KC    = 2048;    // centroids
constexpr int FCAP  = 4096;    // max flagged rows handled exactly
constexpr int NK    = DD / 32; // 16 K-steps

typedef _Float16 half8  __attribute__((ext_vector_type(8)));
typedef _Float16 half4v __attribute__((ext_vector_type(4)));
typedef float    f32x4  __attribute__((ext_vector_type(4)));

// ---------------- prep: x -> fp16 (with eps) --------------------------------
__global__ __launch_bounds__(256) void prep_x(const float* __restrict__ x,
                                              _Float16* __restrict__ xh) {
    size_t i = ((size_t)blockIdx.x * 256 + threadIdx.x) * 4;
    float4 v = *(const float4*)(x + i);
    half4v h;
    h[0] = (_Float16)(v.x + EPS); h[1] = (_Float16)(v.y + EPS);
    h[2] = (_Float16)(v.z + EPS); h[3] = (_Float16)(v.w + EPS);
    *(half4v*)(xh + i) = h;
}

// ---------------- prep: centroids -> fp16, plus fp32 csq --------------------
__global__ __launch_bounds__(256) void prep_c(const float* __restrict__ cen,
                                              _Float16* __restrict__ ch,
                                              float* __restrict__ csq) {
    int w = threadIdx.x >> 6, lane = threadIdx.x & 63;
    int c = blockIdx.x * 4 + w;                    // grid 512 -> 2048 rows
    const float* row = cen + (size_t)c * DD;
    float4 v0 = *(const float4*)(row + lane * 8);
    float4 v1 = *(const float4*)(row + lane * 8 + 4);
    half8 h;
    h[0] = (_Float16)v0.x; h[1] = (_Float16)v0.y; h[2] = (_Float16)v0.z; h[3] = (_Float16)v0.w;
    h[4] = (_Float16)v1.x; h[5] = (_Float16)v1.y; h[6] = (_Float16)v1.z; h[7] = (_Float16)v1.w;
    *(half8*)(ch + (size_t)c * DD + lane * 8) = h;
    float s = v0.x*v0.x + v0.y*v0.y + v0.z*v0.z + v0.w*v0.w
            + v1.x*v1.x + v1.y*v1.y + v1.z*v1.z + v1.w*v1.w;
    #pragma unroll
    for (int off = 32; off > 0; off >>= 1) s += __shfl_down(s, off, 64);
    if (lane == 0) csq[c] = s;
}

// ---------------- coarse fp16 MFMA distance + per-row top2 ------------------
// 128x128 tile, 4 waves of 64x64. A 3-buf (stage k+2), B 2-buf (stage k+1),
// counted s_waitcnt vmcnt(2) + raw s_barrier per K-step. LDS 40KB.
__global__ __launch_bounds__(256, 4) void dist_f16(const _Float16* __restrict__ xh,
                                                   const _Float16* __restrict__ ch,
                                                   const float* __restrict__ csq,
                                                   float* __restrict__ pbest,
                                                   float* __restrict__ psec,
                                                   int*   __restrict__ pidx) {
    // A tiles: smem + {0,1,2}*4096 halfs; B tiles: smem + 12288 + {0,1}*4096.
    __shared__ __align__(16) _Float16 smem[5 * 4096];     // 40 KB exactly

    const int tid = threadIdx.x;
    const int w = tid >> 6, lane = tid & 63;
    const int wr = w >> 1, wc = w & 1;
    const int quad = lane >> 4, u = lane & 15;
    const int rowBase = blockIdx.x * 128;
    const int colBase = blockIdx.y * 128;

    // csq loads pinned before the pipeline (cannot cross the asm fences).
    float cq[4];
    #pragma unroll
    for (int fc = 0; fc < 4; fc++) cq[fc] = csq[colBase + wc * 64 + fc * 16 + u];

    // Staging granules (16B each), g in [0,512): LDS row g>>2, slot g&3.
    const int g0 = 128 * w + lane;
    const int g1 = g0 + 64;
    const int r0 = g0 >> 2, h0 = g0 & 3;
    const int r1 = g1 >> 2, h1 = g1 & 3;
    const _Float16* pa0 = xh + (size_t)(rowBase + r0) * DD + h0 * 8;
    const _Float16* pa1 = xh + (size_t)(rowBase + r1) * DD + h1 * 8;
    const _Float16* pb0 = ch + (size_t)(colBase + r0) * DD + h0 * 8;
    const _Float16* pb1 = ch + (size_t)(colBase + r1) * DD + h1 * 8;

    auto stageA = [&](int kt) {   // 2 global_load_lds per thread
        _Float16* dst = smem + (kt % 3) * 4096;
        const int off = kt * 32;
        __builtin_amdgcn_global_load_lds(
            (const __attribute__((address_space(1))) void*)(pa0 + off),
            (__attribute__((address_space(3))) void*)(dst + g0 * 8), 16, 0, 0);
        __builtin_amdgcn_global_load_lds(
            (const __attribute__((address_space(1))) void*)(pa1 + off),
            (__attribute__((address_space(3))) void*)(dst + g1 * 8), 16, 0, 0);
    };
    auto stageB = [&](int kt) {   // 2 global_load_lds per thread
        _Float16* dst = smem + 12288 + (kt % 2) * 4096;
        const int off = kt * 32;
        __builtin_amdgcn_global_load_lds(
            (const __attribute__((address_space(1))) void*)(pb0 + off),
            (__attribute__((address_space(3))) void*)(dst + g0 * 8), 16, 0, 0);
        __builtin_amdgcn_global_load_lds(
            (const __attribute__((address_space(1))) void*)(pb1 + off),
            (__attribute__((address_space(3))) void*)(dst + g1 * 8), 16, 0, 0);
    };

    f32x4 acc[4][4] = {};

    // prologue: queue = [A0, B0, A1] (6 loads outstanding)
    stageA(0); stageB(0); stageA(1);

    #pragma unroll
    for (int kc = 0; kc < NK; kc++) {
        // wait for tiles A(kc), B(kc); leave A(kc+1)'s 2 loads in flight.
        if (kc + 1 < NK) asm volatile("s_waitcnt vmcnt(2)" ::: "memory");
        else             asm volatile("s_waitcnt vmcnt(0)" ::: "memory");
        __builtin_amdgcn_s_barrier();
        asm volatile("" ::: "memory");
        __builtin_amdgcn_sched_barrier(0);

        if (kc + 1 < NK) stageB(kc + 1);   // into bbuf[(kc+1)%2] (read kc-1, retired)
        if (kc + 2 < NK) stageA(kc + 2);   // into abuf[(kc+2)%3] (read kc-1, retired)

        const _Float16* abuf = smem + (kc % 3) * 4096;
        const _Float16* bbuf = smem + 12288 + (kc % 2) * 4096;
        half8 af[4], bf[4];
        #pragma unroll
        for (int f = 0; f < 4; f++) {
            af[f] = *(const half8*)(abuf + (wr * 64 + f * 16 + u) * 32 + quad * 8);
            bf[f] = *(const half8*)(bbuf + (wc * 64 + f * 16 + u) * 32 + quad * 8);
        }
        #pragma unroll
        for (int fr = 0; fr < 4; fr++)
            #pragma unroll
            for (int fc = 0; fc < 4; fc++)
                acc[fr][fc] = __builtin_amdgcn_mfma_f32_16x16x32_f16(af[fr], bf[fc], acc[fr][fc], 0, 0, 0);
    }

    __syncthreads();   // all LDS reads retired; safe to overlay epilogue staging

    // epilogue staging overlays the A-buffers (3 KB of 40 KB).
    float* ebf = (float*)smem;           // [4][64]
    float* esf = ebf + 256;              // [4][64]
    int*   eif = (int*)(esf + 256);      // [4][64]

    const int cbi = blockIdx.y * 2 + wc;
    const int colQuadBase = colBase + wc * 64;

    #pragma unroll
    for (int fr = 0; fr < 4; fr++) {
        #pragma unroll
        for (int reg = 0; reg < 4; reg++) {
            float vv[4];
            #pragma unroll
            for (int fc = 0; fc < 4; fc++) vv[fc] = cq[fc] - 2.0f * acc[fr][fc][reg];
            // top2 of 4 (min/max network); no coarse tie-break needed
            float mn01 = fminf(vv[0], vv[1]), mx01 = fmaxf(vv[0], vv[1]);
            float mn23 = fminf(vv[2], vv[3]), mx23 = fmaxf(vv[2], vv[3]);
            float b = fminf(mn01, mn23);
            float s = fminf(fmaxf(mn01, mn23), fminf(mx01, mx23));
            #pragma unroll
            for (int m = 1; m < 16; m <<= 1) {   // butterfly within quad
                float ob = __shfl_xor(b, m, 64);
                float os = __shfl_xor(s, m, 64);
                s = fminf(fminf(s, os), fmaxf(b, ob));
                b = fminf(b, ob);
            }
            int bi = 0x7fffffff;
            #pragma unroll
            for (int fc = 0; fc < 4; fc++) {
                unsigned long long mm = __ballot(vv[fc] == b);
                unsigned q16 = (unsigned)((mm >> (quad * 16)) & 0xFFFFu);
                if (bi == 0x7fffffff && q16)
                    bi = colQuadBase + fc * 16 + (__ffs(q16) - 1);
            }
            if (u == 0) {
                int rl = fr * 16 + quad * 4 + reg;   // local row 0..63
                ebf[w * 64 + rl] = b; esf[w * 64 + rl] = s; eif[w * 64 + rl] = bi;
            }
        }
    }
    __syncthreads();
    // coalesced partial stores: 64 contiguous rows per wave per array
    {
        const int base = cbi * BROWS + rowBase + wr * 64;
        pbest[base + lane] = ebf[w * 64 + lane];
        psec [base + lane] = esf[w * 64 + lane];
        pidx [base + lane] = eif[w * 64 + lane];
    }
}

// ---------------- merge 32 partials per row; flag near-ties -----------------
__global__ __launch_bounds__(256) void reduce_rows(const float* __restrict__ pbest,
                                                   const float* __restrict__ psec,
                                                   const int* __restrict__ pidx,
                                                   float* __restrict__ out,
                                                   int* __restrict__ labels,
                                                   int* __restrict__ rlist,
                                                   int* __restrict__ ctr) {
    int row = blockIdx.x * 256 + threadIdx.x;    // grid 128
    float b = 3.4e38f, s = 3.4e38f; int bi = 0x7fffffff;
    for (int p = 0; p < 32; p++) {
        float v  = pbest[p * BROWS + row];
        float sv = psec [p * BROWS + row];
        int   vi = pidx [p * BROWS + row];
        if (v < b) { s = fminf(b, fminf(s, sv)); b = v; bi = vi; }
        else       { s = fminf(s, fminf(v, sv)); }
    }
    out[row] = (float)bi;
    labels[row] = bi;
    if (s - b < TAU) {
        int slot = atomicAdd(ctr, 1);
        if (slot < FCAP) rlist[slot] = row;
    }
}

// ---------------- exact fp32 rescore of flagged rows ------------------------
__global__ __launch_bounds__(256, 2) void fixup_dist(const float* __restrict__ x,
                                                     const float* __restrict__ cen,
                                                     const float* __restrict__ csq,
                                                     const int* __restrict__ rlist,
                                                     const int* __restrict__ ctr,
                                                     float* __restrict__ fbest,
                                                     int*   __restrict__ fidx) {
    int n = min(*ctr, FCAP);
    int tilebase = blockIdx.y * 128;
    if (tilebase >= n) return;

    __shared__ float xs[16][132];
    __shared__ float cs[16][132];
    __shared__ float redv[128][17];
    __shared__ int   redi[128][17];
    __shared__ int   rows[128];

    const int tid = threadIdx.x;
    if (tid < 128) rows[tid] = rlist[tilebase + tid];
    __syncthreads();

    const int ty = tid >> 4, tx = tid & 15;
    const int colBase = blockIdx.x * 128;

    float acc[8][8] = {};
    for (int dk = 0; dk < DD; dk += 16) {
        #pragma unroll
        for (int sI = 0; sI < 2; sI++) {
            int id = tid + sI * 256;
            int r  = id >> 2;
            int dc = (id & 3) * 4;
            float4 xv = *(const float4*)(x + (size_t)rows[r] * DD + dk + dc);
            xs[dc + 0][r] = xv.x + EPS; xs[dc + 1][r] = xv.y + EPS;
            xs[dc + 2][r] = xv.z + EPS; xs[dc + 3][r] = xv.w + EPS;
            float4 cv = *(const float4*)(cen + (size_t)(colBase + r) * DD + dk + dc);
            cs[dc + 0][r] = cv.x; cs[dc + 1][r] = cv.y;
            cs[dc + 2][r] = cv.z; cs[dc + 3][r] = cv.w;
        }
        __syncthreads();
        #pragma unroll
        for (int k = 0; k < 16; k++) {
            float4 a0 = *(const float4*)&xs[k][ty * 4];
            float4 a1 = *(const float4*)&xs[k][64 + ty * 4];
            float4 b0 = *(const float4*)&cs[k][tx * 4];
            float4 b1 = *(const float4*)&cs[k][64 + tx * 4];
            float a[8] = {a0.x, a0.y, a0.z, a0.w, a1.x, a1.y, a1.z, a1.w};
            float b[8] = {b0.x, b0.y, b0.z, b0.w, b1.x, b1.y, b1.z, b1.w};
            #pragma unroll
            for (int i = 0; i < 8; i++)
                #pragma unroll
                for (int j = 0; j < 8; j++)
                    acc[i][j] += a[i] * b[j];
        }
        __syncthreads();
    }

    float bv[8]; int bix[8];
    #pragma unroll
    for (int i = 0; i < 8; i++) { bv[i] = 3.4e38f; bix[i] = 0x7fffffff; }
    #pragma unroll
    for (int j = 0; j < 8; j++) {
        int col = colBase + ((j < 4) ? (tx * 4 + j) : (64 + tx * 4 + (j - 4)));
        float cq = csq[col];
        #pragma unroll
        for (int i = 0; i < 8; i++) {
            float v = cq - 2.0f * acc[i][j];
            if (v < bv[i] || (v == bv[i] && col < bix[i])) { bv[i] = v; bix[i] = col; }
        }
    }
    #pragma unroll
    for (int i = 0; i < 8; i++) {
        int r = (i < 4) ? (ty * 4 + i) : (64 + ty * 4 + (i - 4));
        redv[r][tx] = bv[i]; redi[r][tx] = bix[i];
    }
    __syncthreads();
    if (tid < 128) {
        float b = 3.4e38f; int bi = 0x7fffffff;
        #pragma unroll
        for (int t = 0; t < 16; t++) {
            float v = redv[tid][t]; int ix = redi[tid][t];
            if (v < b || (v == b && ix < bi)) { b = v; bi = ix; }
        }
        fbest[blockIdx.x * FCAP + tilebase + tid] = b;
        fidx [blockIdx.x * FCAP + tilebase + tid] = bi;
    }
}

__global__ __launch_bounds__(256) void fixup_reduce(const float* __restrict__ fbest,
                                                    const int* __restrict__ fidx,
                                                    const int* __restrict__ rlist,
                                                    const int* __restrict__ ctr,
                                                    float* __restrict__ out,
                                                    int* __restrict__ labels) {
    int s = blockIdx.x * 256 + threadIdx.x;      // grid 16
    int n = min(*ctr, FCAP);
    if (s >= n) return;
    float b = 3.4e38f; int bi = 0x7fffffff;
    for (int c = 0; c < 16; c++) {
        float v = fbest[c * FCAP + s]; int ix = fidx[c * FCAP + s];
        if (v < b || (v == b && ix < bi)) { b = v; bi = ix; }
    }
    int row = rlist[s];
    out[row] = (float)bi;
    labels[row] = bi;
}

// ---------------- gather assigned centroids ---------------------------------
__global__ __launch_bounds__(256) void gather(const float* __restrict__ cen,
                                              const int* __restrict__ labels,
                                              float* __restrict__ out) {
    __shared__ int lab[8];
    const int tid = threadIdx.x;
    const int rowBase = blockIdx.x * 8;
    if (tid < 8) lab[tid] = labels[rowBase + tid];
    __syncthreads();
    float* assigned = out + BROWS;
    #pragma unroll 4
    for (int s = tid; s < 8 * 128; s += 256) {
        int r = s >> 7;
        int f = (s & 127) * 4;
        float4 v = *(const float4*)(cen + (size_t)lab[r] * DD + f);
        *(float4*)(assigned + (size_t)(rowBase + r) * DD + f) = v;
    }
}

extern "C" void kernel_launch(void* const* d_in, const int* in_sizes, int n_in,
                              void* d_out, int out_size, void* d_ws, size_t ws_size,
                              hipStream_t stream) {
    const float* x   = (const float*)d_in[0];
    const float* cen = (const float*)d_in[1];

    char* base = (char*)d_ws;
    _Float16* xh   = (_Float16*)(base);                    // 32 MB
    _Float16* ch   = (_Float16*)(base + 33554432);         // 2 MB
    float* csq     = (float*)(base + 35651584);            // 8 KB
    float* pbest   = (float*)(base + 35659776);            // 4 MB
    float* psec    = (float*)(base + 39854080);            // 4 MB
    int*   pidx    = (int*)  (base + 44048384);            // 4 MB
    int*   labels  = (int*)  (base + 48242688);            // 128 KB
    int*   rlist   = (int*)  (base + 48373760);            // 16 KB
    float* fbest   = (float*)(base + 48390144);            // 256 KB
    int*   fidx    = (int*)  (base + 48652288);            // 256 KB
    int*   ctr     = (int*)  (base + 48914432);            // 4 B

    hipMemsetAsync(ctr, 0, 4, stream);
    hipMemsetAsync(rlist, 0, FCAP * 4, stream);

    prep_x<<<BROWS * DD / 4 / 256, 256, 0, stream>>>(x, xh);
    prep_c<<<KC / 4, 256, 0, stream>>>(cen, ch, csq);
    dist_f16<<<dim3(BROWS / 128, KC / 128), 256, 0, stream>>>(xh, ch, csq, pbest, psec, pidx);
    reduce_rows<<<BROWS / 256, 256, 0, stream>>>(pbest, psec, pidx, (float*)d_out, labels, rlist, ctr);
    fixup_dist<<<dim3(KC / 128, FCAP / 128), 256, 0, stream>>>(x, cen, csq, rlist, ctr, fbest, fidx);
    fixup_reduce<<<FCAP / 256, 256, 0, stream>>>(fbest, fidx, rlist, ctr, (float*)d_out, labels);
    gather<<<BROWS / 8, 256, 0, stream>>>(cen, labels, (float*)d_out);
}